// Round 1
// baseline (110.632 us; speedup 1.0000x reference)
//
#include <hip/hip_runtime.h>
#include <math.h>

#define Bsz 8
#define CIN 3
#define CC 8
#define Hh 512
#define Ww 512
#define HW (Hh*Ww)

__device__ __forceinline__ int refl(int i, int n) {
    if (i < 0) return -i;
    if (i >= n) return 2*n - 2 - i;
    return i;
}

// K0: A = Psx @ (Pg @ We), B = Psy @ (Pg @ We)   (each 8x3) -> mats[0..23], mats[24..47]
__global__ void k_mats(const float* __restrict__ we, const float* __restrict__ pg,
                       const float* __restrict__ psx, const float* __restrict__ psy,
                       float* __restrict__ mats) {
    if (threadIdx.x == 0 && blockIdx.x == 0) {
        float M1[CC][CIN];
        for (int o = 0; o < CC; ++o)
            for (int c = 0; c < CIN; ++c) {
                float a = 0.f;
                for (int k = 0; k < CC; ++k) a += pg[o*CC+k] * we[k*CIN+c];
                M1[o][c] = a;
            }
        for (int o = 0; o < CC; ++o)
            for (int c = 0; c < CIN; ++c) {
                float a = 0.f, b = 0.f;
                for (int k = 0; k < CC; ++k) { a += psx[o*CC+k]*M1[k][c]; b += psy[o*CC+k]*M1[k][c]; }
                mats[o*CIN+c]      = a;
                mats[24 + o*CIN+c] = b;
            }
    }
}

// K1: blur(reflect) -> sobel -> gx,gy (via A,B) -> mag(8ch), s=sum(mag), idx packed (3b x 8)
__global__ __launch_bounds__(256) void k_grad(const float* __restrict__ x,
        const float* __restrict__ mats,
        float* __restrict__ magB, float* __restrict__ sB, unsigned* __restrict__ idxB,
        float wc, float we_, float wk) {
    __shared__ float xs[CIN][20][20];
    __shared__ float bs[CIN][18][18];
    __shared__ float sA[24], sBm[24];
    const int b  = blockIdx.z;
    const int x0 = blockIdx.x * 16, y0 = blockIdx.y * 16;
    const int t  = threadIdx.y * 16 + threadIdx.x;

    if (t < 48) { float v = mats[t]; if (t < 24) sA[t] = v; else sBm[t-24] = v; }

    for (int i = t; i < CIN*20*20; i += 256) {
        int c = i / 400, j = i % 400, r = j / 20, cc = j % 20;
        int yy = refl(y0 - 2 + r, Hh), xx = refl(x0 - 2 + cc, Ww);
        xs[c][r][cc] = x[((size_t)(b*CIN + c)*Hh + yy)*Ww + xx];
    }
    __syncthreads();

    for (int i = t; i < CIN*18*18; i += 256) {
        int c = i / 324, j = i % 324, r = j / 18, cc = j % 18;
        float v =
          wk*(xs[c][r][cc]   + xs[c][r][cc+2]   + xs[c][r+2][cc]   + xs[c][r+2][cc+2]) +
          we_*(xs[c][r][cc+1] + xs[c][r+1][cc]  + xs[c][r+1][cc+2] + xs[c][r+2][cc+1]) +
          wc * xs[c][r+1][cc+1];
        bs[c][r][cc] = v;
    }
    __syncthreads();

    const int ty = threadIdx.y, tx = threadIdx.x;
    const int cy = ty + 1, cx = tx + 1;
    float txv[3], tyv[3];
    #pragma unroll
    for (int c = 0; c < CIN; ++c) {
        float v00 = bs[c][cy-1][cx-1], v01 = bs[c][cy-1][cx], v02 = bs[c][cy-1][cx+1];
        float v10 = bs[c][cy  ][cx-1],                        v12 = bs[c][cy  ][cx+1];
        float v20 = bs[c][cy+1][cx-1], v21 = bs[c][cy+1][cx], v22 = bs[c][cy+1][cx+1];
        txv[c] = 0.5f*(v02 - v00) + (v12 - v10) + 0.5f*(v22 - v20);
        tyv[c] = 0.5f*(v20 - v00) + (v21 - v01) + 0.5f*(v22 - v02);
    }

    const int yy = y0 + ty, xx = x0 + tx;
    const int p  = yy * Ww + xx;
    float s = 0.f;
    unsigned pack = 0;
    #pragma unroll
    for (int o = 0; o < CC; ++o) {
        float gx = sA[o*3+0]*txv[0] + sA[o*3+1]*txv[1] + sA[o*3+2]*txv[2];
        float gy = sBm[o*3+0]*tyv[0] + sBm[o*3+1]*tyv[1] + sBm[o*3+2]*tyv[2];
        float mag = sqrtf(gx*gx + gy*gy + 1e-10f);
        magB[(size_t)(b*CC + o)*HW + p] = mag;
        s += mag;
        // deg/45 = atan2 * (4/pi); round-half-even like jnp.round; mod 8
        float d45 = atan2f(gy, gx) * 1.27323954473516268615f;
        int r = (int)rintf(d45);        // in [-4,4]
        pack |= (unsigned)(r & 7) << (3*o);
    }
    sB[(size_t)b*HW + p]   = s;
    idxB[(size_t)b*HW + p] = pack;
}

__device__ __forceinline__ float pick8(int i, float a0, float a1, float a2, float a3,
                                       float a4, float a5, float a6, float a7) {
    float r = a0;
    r = (i == 1) ? a1 : r;
    r = (i == 2) ? a2 : r;
    r = (i == 3) ? a3 : r;
    r = (i == 4) ? a4 : r;
    r = (i == 5) ? a5 : r;
    r = (i == 6) ? a6 : r;
    r = (i == 7) ? a7 : r;
    return r;
}

__device__ __forceinline__ float sigm(float z) { return 1.f / (1.f + expf(-z)); }

// K2: dirs (zero-pad diffs of s), NMS, soft double-threshold, merge -> m
__global__ __launch_bounds__(256) void k_nms(const float* __restrict__ magB,
        const float* __restrict__ sB, const unsigned* __restrict__ idxB,
        const float* __restrict__ wmerge, const float* __restrict__ lowt,
        const float* __restrict__ hight, float* __restrict__ mB) {
    int gid = blockIdx.x * 256 + threadIdx.x;
    if (gid >= Bsz*HW) return;
    int b = gid / HW, p = gid % HW;
    int y = p / Ww, xx = p % Ww;
    float sc = sB[gid];
    // dir order: E, SE, S, SW, W, NW, N, NE  (center minus neighbor, zero pad)
    const int DY[8] = {0, 1, 1, 1, 0, -1, -1, -1};
    const int DX[8] = {1, 1, 0, -1, -1, -1, 0, 1};
    float d0, d1, d2, d3, d4, d5, d6, d7;
    float* dd[8] = {&d0,&d1,&d2,&d3,&d4,&d5,&d6,&d7};
    #pragma unroll
    for (int d = 0; d < 8; ++d) {
        int ny = y + DY[d], nx = xx + DX[d];
        float sn = (ny >= 0 && ny < Hh && nx >= 0 && nx < Ww) ? sB[(size_t)b*HW + ny*Ww + nx] : 0.f;
        *dd[d] = sc - sn;
    }
    unsigned pack = idxB[gid];
    float m = 0.f;
    #pragma unroll
    for (int o = 0; o < CC; ++o) {
        float mag = magB[(size_t)(b*CC + o)*HW + p];
        int i  = (pack >> (3*o)) & 7;
        int i4 = (i + 4) & 7;
        float pos = pick8(i,  d0,d1,d2,d3,d4,d5,d6,d7);
        float neg = pick8(i4, d0,d1,d2,d3,d4,d5,d6,d7);
        float nms = (pos > 0.f && neg > 0.f) ? mag : 0.f;
        float hi = hight[o], lo = lowt[o];
        float strong = sigm(1000.f * (nms - hi));
        float weak   = 0.5f * (sigm(1000.f * (hi - nms)) - sigm(1000.f * (lo - nms)));
        m += wmerge[o] * (weak + strong);
    }
    mB[gid] = m;
}

// K3: one-step hysteresis (reflect pad) -> out
__global__ __launch_bounds__(256) void k_hyst(const float* __restrict__ mB,
                                              float* __restrict__ out) {
    int gid = blockIdx.x * 256 + threadIdx.x;
    if (gid >= Bsz*HW) return;
    int b = gid / HW, p = gid % HW;
    int y = p / Ww, xx = p % Ww;
    float mc = mB[gid];
    float hyst = 0.f;
    #pragma unroll
    for (int dy = -1; dy <= 1; ++dy) {
        #pragma unroll
        for (int dx = -1; dx <= 1; ++dx) {
            int ny = refl(y + dy, Hh), nx = refl(xx + dx, Ww);
            float mv = mB[(size_t)b*HW + ny*Ww + nx];
            hyst += (mv == 1.0f) ? mv : 0.f;
        }
    }
    hyst *= 1.25f;
    float strong_c = (mc == 1.0f) ? mc : 0.f;
    bool masked = (mc == 0.5f);
    out[gid] = (((hyst > 1.0f) && masked) ? mc : 0.f) + strong_c;
}

extern "C" void kernel_launch(void* const* d_in, const int* in_sizes, int n_in,
                              void* d_out, int out_size, void* d_ws, size_t ws_size,
                              hipStream_t stream) {
    const float* x    = (const float*)d_in[0];
    const float* we   = (const float*)d_in[1];
    const float* pg   = (const float*)d_in[2];
    const float* psx  = (const float*)d_in[3];
    const float* psy  = (const float*)d_in[4];
    const float* wm   = (const float*)d_in[5];
    const float* lowt = (const float*)d_in[6];
    const float* hit  = (const float*)d_in[7];

    // ws partition (floats)
    float* ws = (float*)d_ws;
    float*    mats = ws;                                   // 64
    float*    magB = ws + 64;                              // 8*8*512*512 = 16,777,216
    float*    sB   = magB + (size_t)Bsz*CC*HW;             // 2,097,152
    unsigned* idxB = (unsigned*)(sB + (size_t)Bsz*HW);     // 2,097,152
    float*    mB   = (float*)(idxB + (size_t)Bsz*HW);      // 2,097,152
    float*    outp = (float*)d_out;

    // gaussian 3x3 (sigma=3) weights, normalized — computed in double like numpy
    double e1 = exp(-1.0/18.0), e2 = exp(-2.0/18.0);
    double sum = 1.0 + 4.0*e1 + 4.0*e2;
    float wc = (float)(1.0/sum), wE = (float)(e1/sum), wk = (float)(e2/sum);

    k_mats<<<1, 64, 0, stream>>>(we, pg, psx, psy, mats);
    k_grad<<<dim3(Ww/16, Hh/16, Bsz), dim3(16,16), 0, stream>>>(x, mats, magB, sB, idxB, wc, wE, wk);
    int n = Bsz * HW;
    k_nms<<<(n + 255)/256, 256, 0, stream>>>(magB, sB, idxB, wm, lowt, hit, mB);
    k_hyst<<<(n + 255)/256, 256, 0, stream>>>(mB, outp);
}

// Round 2
// 98.775 us; speedup vs baseline: 1.1200x; 1.1200x over previous
//
#include <hip/hip_runtime.h>
#include <math.h>

#define Bsz 8
#define CIN 3
#define CC 8
#define Hh 512
#define Ww 512
#define HW (Hh*Ww)
#define T 16

__device__ __forceinline__ int refl(int i, int n) {
    i = (i < 0) ? -i : i;
    return (i >= n) ? (2*n - 2 - i) : i;
}

__device__ __forceinline__ float sigf(float z) {
    // fast sigmoid; saturates exactly to 0/1 for |z| large (expf->inf/0)
    return __builtin_amdgcn_rcpf(1.f + __expf(-z));
}

// Fully fused Canny pipeline. Per 16x16 output tile:
//   A: load reflect-extended x window (24^2 x 3) to LDS
//   B: blur (B~ = reflect-extended blur, 22^2 x 3)
//   C: sobel -> gx,gy per 8ch via folded 8x3 mats -> mag(18^2x8), idx packed, s(20^2)
//   D: dirs from s (zero-pad), NMS via 4-bit axis mask, soft threshold, merge -> m(18^2)
//   E: hysteresis (reflect on m) -> out
__global__ __launch_bounds__(256) void k_fused(
    const float* __restrict__ x,
    const float* __restrict__ we, const float* __restrict__ pg,
    const float* __restrict__ psx, const float* __restrict__ psy,
    const float* __restrict__ wm, const float* __restrict__ lowt,
    const float* __restrict__ hight,
    float* __restrict__ out,
    float wc, float wE, float wk)
{
    __shared__ float xs[CIN][24][24];
    __shared__ float bl[CIN][22][22];
    __shared__ float sS[20][20];
    __shared__ float magS[CC][18][18];
    __shared__ unsigned idxS[18][18];
    __shared__ float mS[18][18];
    __shared__ float sA[24], sBv[24], M1[24];
    __shared__ float wmS[8], loS[8], hiS[8];

    const int b  = blockIdx.z;
    const int x0 = blockIdx.x * T, y0 = blockIdx.y * T;
    const int tx = threadIdx.x, ty = threadIdx.y;
    const int t  = ty * 16 + tx;

    // phase 0a: M1 = Pg @ We (8x3); load thresholds/merge weights
    if (t < 24) {
        int o = t / 3, c = t % 3;
        float a = 0.f;
        #pragma unroll
        for (int k = 0; k < 8; ++k) a += pg[o*8+k] * we[k*3+c];
        M1[t] = a;
    } else if (t < 32) {
        wmS[t-24] = wm[t-24];
        loS[t-24] = lowt[t-24];
        hiS[t-24] = hight[t-24];
    }

    // phase A: reflect-extended x window
    const float* xb = x + (size_t)b * CIN * HW;
    for (int i = t; i < CIN*24*24; i += 256) {
        int c = i / 576, j = i % 576, r = j / 24, cc = j % 24;
        int yy = refl(y0 - 4 + r, Hh), xx = refl(x0 - 4 + cc, Ww);
        xs[c][r][cc] = xb[(size_t)c*HW + yy*Ww + xx];
    }
    __syncthreads();

    // phase 0b: sA = Psx@M1, sBv = Psy@M1   (each 8x3)
    if (t < 24) {
        int o = t / 3, c = t % 3;
        float a = 0.f, bb = 0.f;
        #pragma unroll
        for (int k = 0; k < 8; ++k) { a += psx[o*8+k]*M1[k*3+c]; bb += psy[o*8+k]*M1[k*3+c]; }
        sA[t] = a; sBv[t] = bb;
    }

    // phase B: B~ window (blur at reflected coords; double reflection handled via xs window)
    for (int i = t; i < CIN*22*22; i += 256) {
        int c = i / 484, j = i % 484, r = j / 22, cc = j % 22;
        int iy = refl(y0 - 3 + r, Hh) - (y0 - 4);
        int ix = refl(x0 - 3 + cc, Ww) - (x0 - 4);
        float v =
          wk*(xs[c][iy-1][ix-1] + xs[c][iy-1][ix+1] + xs[c][iy+1][ix-1] + xs[c][iy+1][ix+1]) +
          wE*(xs[c][iy-1][ix]   + xs[c][iy][ix-1]   + xs[c][iy][ix+1]   + xs[c][iy+1][ix]) +
          wc* xs[c][iy][ix];
        bl[c][r][cc] = v;
    }
    __syncthreads();

    // phase C: sobel + per-channel gx/gy/mag/idx, s = sum(mag)
    for (int i = t; i < 20*20; i += 256) {
        int r = i / 20, cc = i % 20;
        float txv[3], tyv[3];
        #pragma unroll
        for (int c = 0; c < CIN; ++c) {
            float v00 = bl[c][r][cc],   v01 = bl[c][r][cc+1],   v02 = bl[c][r][cc+2];
            float v10 = bl[c][r+1][cc],                         v12 = bl[c][r+1][cc+2];
            float v20 = bl[c][r+2][cc], v21 = bl[c][r+2][cc+1], v22 = bl[c][r+2][cc+2];
            txv[c] = 0.5f*(v02 - v00) + (v12 - v10) + 0.5f*(v22 - v20);
            tyv[c] = 0.5f*(v20 - v00) + (v21 - v01) + 0.5f*(v22 - v02);
        }
        int gy = y0 - 2 + r, gxp = x0 - 2 + cc;
        bool inimg = (gy >= 0 && gy < Hh && gxp >= 0 && gxp < Ww);
        bool inD   = (r >= 1 && r < 19 && cc >= 1 && cc < 19);
        float s = 0.f;
        unsigned pack = 0;
        #pragma unroll
        for (int o = 0; o < CC; ++o) {
            float gx  = sA[o*3]*txv[0]  + sA[o*3+1]*txv[1]  + sA[o*3+2]*txv[2];
            float gyy = sBv[o*3]*tyv[0] + sBv[o*3+1]*tyv[1] + sBv[o*3+2]*tyv[2];
            float mag = sqrtf(gx*gx + gyy*gyy + 1e-10f);
            s += mag;
            // octant classification == mod(round(atan2*4/pi),8); tan(22.5deg)=0.41421356
            float ax = fabsf(gx), ay = fabsf(gyy);
            int id;
            if (ay <= 0.41421356237f * ax)      id = (gx  >= 0.f) ? 0 : 4;
            else if (ax <= 0.41421356237f * ay) id = (gyy >= 0.f) ? 2 : 6;
            else id = (gyy >= 0.f) ? ((gx >= 0.f) ? 1 : 3) : ((gx >= 0.f) ? 7 : 5);
            pack |= (unsigned)id << (3*o);
            if (inD) magS[o][r-1][cc-1] = mag;
        }
        sS[r][cc] = inimg ? s : 0.f;
        if (inD) idxS[r-1][cc-1] = pack;
    }
    __syncthreads();

    // phase D: NMS + soft double threshold + merge -> m
    for (int i = t; i < 18*18; i += 256) {
        int rd = i / 18, cd = i % 18;
        float sc  = sS[rd+1][cd+1];
        float sE  = sS[rd+1][cd+2], sW  = sS[rd+1][cd];
        float sSe = sS[rd+2][cd+2], sNw = sS[rd][cd];
        float sSo = sS[rd+2][cd+1], sNo = sS[rd][cd+1];
        float sSw = sS[rd+2][cd],   sNe = sS[rd][cd+2];
        // cond(idx) depends only on idx&3 (opposite-neighbor pairs)
        unsigned mask = 0;
        mask |= (sc > sE  && sc > sW ) ? 1u : 0u;
        mask |= (sc > sSe && sc > sNw) ? 2u : 0u;
        mask |= (sc > sSo && sc > sNo) ? 4u : 0u;
        mask |= (sc > sSw && sc > sNe) ? 8u : 0u;
        unsigned pack = idxS[rd][cd];
        float m = 0.f;
        #pragma unroll
        for (int o = 0; o < CC; ++o) {
            float mag = magS[o][rd][cd];
            int id = (pack >> (3*o)) & 7;
            float nms = ((mask >> (id & 3)) & 1u) ? mag : 0.f;
            float hi = hiS[o], lo = loS[o];
            float strong = sigf(1000.f * (nms - hi));
            float weak   = 0.5f * (sigf(1000.f * (hi - nms)) - sigf(1000.f * (lo - nms)));
            m += wmS[o] * (weak + strong);
        }
        mS[rd][cd] = m;
    }
    __syncthreads();

    // phase E: one-step hysteresis (reflect on m) -> out
    {
        int y = y0 + ty, xg = x0 + tx;
        float mc = mS[ty+1][tx+1];
        float hyst = 0.f;
        #pragma unroll
        for (int dy = -1; dy <= 1; ++dy)
            #pragma unroll
            for (int dx = -1; dx <= 1; ++dx) {
                int ly = refl(y + dy, Hh) - (y0 - 1);
                int lx = refl(xg + dx, Ww) - (x0 - 1);
                hyst += (mS[ly][lx] == 1.0f) ? 1.25f : 0.f;
            }
        float strong_c = (mc == 1.0f) ? mc : 0.f;
        out[(size_t)b*HW + (size_t)y*Ww + xg] =
            (((hyst > 1.0f) && (mc == 0.5f)) ? mc : 0.f) + strong_c;
    }
}

extern "C" void kernel_launch(void* const* d_in, const int* in_sizes, int n_in,
                              void* d_out, int out_size, void* d_ws, size_t ws_size,
                              hipStream_t stream) {
    const float* x    = (const float*)d_in[0];
    const float* we   = (const float*)d_in[1];
    const float* pg   = (const float*)d_in[2];
    const float* psx  = (const float*)d_in[3];
    const float* psy  = (const float*)d_in[4];
    const float* wm   = (const float*)d_in[5];
    const float* lowt = (const float*)d_in[6];
    const float* hit  = (const float*)d_in[7];
    float* outp = (float*)d_out;

    // gaussian 3x3 (sigma=3), normalized, computed in double like numpy
    double e1 = exp(-1.0/18.0), e2 = exp(-2.0/18.0);
    double sum = 1.0 + 4.0*e1 + 4.0*e2;
    float wc = (float)(1.0/sum), wE = (float)(e1/sum), wk = (float)(e2/sum);

    k_fused<<<dim3(Ww/T, Hh/T, Bsz), dim3(16,16), 0, stream>>>(
        x, we, pg, psx, psy, wm, lowt, hit, outp, wc, wE, wk);
}

// Round 3
// 59.555 us; speedup vs baseline: 1.8576x; 1.6585x over previous
//
#include <hip/hip_runtime.h>
#include <math.h>

#define Bsz 8
#define HWp (512*512)
#define TS 32
#define SG 36          // s-grid (out + halo 2)
#define MG 34          // m-grid (out + halo 1)
#define XW 40          // x window (out + halo 4)
#define BW 38          // blur window (out + halo 3)
#define NT 512

__device__ __forceinline__ int refl(int i, int n) {
    i = (i < 0) ? -i : i;
    return (i >= n) ? (2*n - 2 - i) : i;
}
__device__ __forceinline__ float sigf(float z) {
    // sigmoid; saturates exactly to 0/1 at |z| large (expf -> inf/0)
    return __builtin_amdgcn_rcpf(1.f + __expf(-z));
}

// A = Psx@(Pg@We), B = Psy@(Pg@We) (each 8x3) -> mats[0..23], mats[24..47]
__global__ void k_mats(const float* __restrict__ we, const float* __restrict__ pg,
                       const float* __restrict__ psx, const float* __restrict__ psy,
                       float* __restrict__ mats) {
    if (threadIdx.x == 0 && blockIdx.x == 0) {
        float M1[8][3];
        for (int o = 0; o < 8; ++o)
            for (int c = 0; c < 3; ++c) {
                float a = 0.f;
                for (int k = 0; k < 8; ++k) a += pg[o*8+k] * we[k*3+c];
                M1[o][c] = a;
            }
        for (int o = 0; o < 8; ++o)
            for (int c = 0; c < 3; ++c) {
                float a = 0.f, b = 0.f;
                for (int k = 0; k < 8; ++k) { a += psx[o*8+k]*M1[k][c]; b += psy[o*8+k]*M1[k][c]; }
                mats[o*3+c]      = a;
                mats[24 + o*3+c] = b;
            }
    }
}

// Fully fused Canny, 32x32 tile / 512 threads. Weights in SGPRs (uniform loads),
// per-channel mag + octant kept in registers between NMS phases, LDS aliased.
__global__ __launch_bounds__(NT) void k_fused(
    const float* __restrict__ x, const float* __restrict__ mats,
    const float* __restrict__ wm, const float* __restrict__ lowt,
    const float* __restrict__ hight,
    float* __restrict__ out, float wc, float wE, float wk)
{
    __shared__ float sm1[3*XW*XW];   // phase A/B: xs ; phase C+: sS(1296) | mS(1156)
    __shared__ float blb[3*BW*BW];

    const int b  = blockIdx.z;
    const int x0 = blockIdx.x*TS, y0 = blockIdx.y*TS;
    const int t  = threadIdx.x;
    const bool inter = (blockIdx.x > 0) && ((int)blockIdx.x < (int)gridDim.x-1) &&
                       (blockIdx.y > 0) && ((int)blockIdx.y < (int)gridDim.y-1);

    const float* xb = x + (size_t)b*3*HWp;

    // ---- phase A: x window (reflect) -> sm1 ----
    if (inter) {
        const float* xo = xb + (size_t)(y0-4)*512 + (x0-4);
        for (int c = 0; c < 3; ++c)
            for (int i = t; i < XW*XW; i += NT) {
                int r = i/XW, cc = i - r*XW;
                sm1[c*(XW*XW)+i] = xo[(size_t)c*HWp + r*512 + cc];
            }
    } else {
        for (int c = 0; c < 3; ++c)
            for (int i = t; i < XW*XW; i += NT) {
                int r = i/XW, cc = i - r*XW;
                sm1[c*(XW*XW)+i] = xb[(size_t)c*HWp + (size_t)refl(y0-4+r,512)*512 + refl(x0-4+cc,512)];
            }
    }
    __syncthreads();

    // ---- phase B: gaussian blur (double-reflect via window) -> blb ----
    if (inter) {
        for (int c = 0; c < 3; ++c)
            for (int i = t; i < BW*BW; i += NT) {
                int r = i/BW, cc = i - r*BW;
                const float* xp = &sm1[c*(XW*XW) + (r+1)*XW + (cc+1)];
                blb[c*(BW*BW)+i] =
                    wk*(xp[-XW-1]+xp[-XW+1]+xp[XW-1]+xp[XW+1]) +
                    wE*(xp[-XW]+xp[-1]+xp[1]+xp[XW]) + wc*xp[0];
            }
    } else {
        for (int c = 0; c < 3; ++c)
            for (int i = t; i < BW*BW; i += NT) {
                int r = i/BW, cc = i - r*BW;
                int iy = refl(y0-3+r,512) - (y0-4);
                int ix = refl(x0-3+cc,512) - (x0-4);
                const float* xp = &sm1[c*(XW*XW) + iy*XW + ix];
                blb[c*(BW*BW)+i] =
                    wk*(xp[-XW-1]+xp[-XW+1]+xp[XW-1]+xp[XW+1]) +
                    wE*(xp[-XW]+xp[-1]+xp[1]+xp[XW]) + wc*xp[0];
            }
    }
    __syncthreads();

    // ---- phase C: sobel -> 8ch gx/gy/mag (regs) + octant (2b) + s -> sS ----
    float mg[3][8];
    unsigned qk[3];
    #pragma unroll
    for (int it = 0; it < 3; ++it) {
        int i = t + it*NT;
        qk[it] = 0;
        if (i < SG*SG) {
            int r = i/SG, cc = i - r*SG;
            float txv[3], tyv[3];
            #pragma unroll
            for (int c = 0; c < 3; ++c) {
                const float* bp = &blb[c*(BW*BW) + r*BW + cc];
                float v00=bp[0],    v01=bp[1],      v02=bp[2];
                float v10=bp[BW],                   v12=bp[BW+2];
                float v20=bp[2*BW], v21=bp[2*BW+1], v22=bp[2*BW+2];
                txv[c] = 0.5f*(v02-v00) + (v12-v10) + 0.5f*(v22-v20);
                tyv[c] = 0.5f*(v20-v00) + (v21-v01) + 0.5f*(v22-v02);
            }
            float s = 0.f; unsigned pk = 0;
            #pragma unroll
            for (int o = 0; o < 8; ++o) {
                float gx  = mats[o*3]*txv[0]    + mats[o*3+1]*txv[1]    + mats[o*3+2]*txv[2];
                float gy  = mats[24+o*3]*tyv[0] + mats[24+o*3+1]*tyv[1] + mats[24+o*3+2]*tyv[2];
                float mgv = __builtin_amdgcn_sqrtf(gx*gx + gy*gy + 1e-10f);
                mg[it][o] = mgv; s += mgv;
                float ax = fabsf(gx), ay = fabsf(gy);
                unsigned qo;
                if (ay <= 0.41421356237309503f*ax)      qo = 0u;         // E/W axis
                else if (ax <= 0.41421356237309503f*ay) qo = 2u;         // N/S axis
                else qo = ((gx >= 0.f) == (gy >= 0.f)) ? 1u : 3u;        // diagonals
                pk |= qo << (2*o);
            }
            qk[it] = pk;
            int gy_ = y0-2+r, gx_ = x0-2+cc;
            bool inimg = ((unsigned)gy_ < 512u) && ((unsigned)gx_ < 512u);
            sm1[i] = inimg ? s : 0.f;      // sS (xs dead after phase B)
        }
    }
    __syncthreads();

    // ---- phase D: NMS + soft double threshold + merge -> mS ----
    float* sS = sm1;
    float* mS = sm1 + SG*SG;
    #pragma unroll
    for (int it = 0; it < 3; ++it) {
        int i = t + it*NT;
        if (i < SG*SG) {
            int r = i/SG, cc = i - r*SG;
            if (r >= 1 && r < SG-1 && cc >= 1 && cc < SG-1) {
                const float* sp = &sS[i];
                float sc = sp[0];
                unsigned mask = 0;
                mask |= ((sc > sp[1])    && (sc > sp[-1]))    ? 1u : 0u;  // E/W
                mask |= ((sc > sp[SG+1]) && (sc > sp[-SG-1])) ? 2u : 0u;  // SE/NW
                mask |= ((sc > sp[SG])   && (sc > sp[-SG]))   ? 4u : 0u;  // S/N
                mask |= ((sc > sp[SG-1]) && (sc > sp[-SG+1])) ? 8u : 0u;  // SW/NE
                unsigned pk = qk[it];
                float m = 0.f;
                #pragma unroll
                for (int o = 0; o < 8; ++o) {
                    float nms = ((mask >> ((pk >> (2*o)) & 3u)) & 1u) ? mg[it][o] : 0.f;
                    // weak+strong == 0.5*(sig(1000(nms-lo)) + sig(1000(nms-hi)))
                    float thr = 0.5f*(sigf(1000.f*(nms - hight[o])) + sigf(1000.f*(nms - lowt[o])));
                    m += wm[o]*thr;
                }
                mS[(r-1)*MG + (cc-1)] = m;
            }
        }
    }
    __syncthreads();

    // ---- phase E: one-step hysteresis (reflect) -> out ----
    for (int i2 = t; i2 < TS*TS; i2 += NT) {
        int ty_ = i2/TS, tx_ = i2 - ty_*TS;
        int y = y0 + ty_, xg = x0 + tx_;
        const float* mp = &mS[(ty_+1)*MG + (tx_+1)];
        float mc = mp[0];
        float hy = 0.f;
        if (inter) {
            #pragma unroll
            for (int dy = -1; dy <= 1; ++dy)
                #pragma unroll
                for (int dx = -1; dx <= 1; ++dx)
                    hy += (mp[dy*MG+dx] == 1.0f) ? 1.25f : 0.f;
        } else {
            #pragma unroll
            for (int dy = -1; dy <= 1; ++dy)
                #pragma unroll
                for (int dx = -1; dx <= 1; ++dx) {
                    int ly = refl(y+dy,512) - (y0-1);
                    int lx = refl(xg+dx,512) - (x0-1);
                    hy += (mS[ly*MG+lx] == 1.0f) ? 1.25f : 0.f;
                }
        }
        float strong = (mc == 1.0f) ? mc : 0.f;
        out[(size_t)b*HWp + (size_t)y*512 + xg] =
            (((hy > 1.0f) && (mc == 0.5f)) ? mc : 0.f) + strong;
    }
}

extern "C" void kernel_launch(void* const* d_in, const int* in_sizes, int n_in,
                              void* d_out, int out_size, void* d_ws, size_t ws_size,
                              hipStream_t stream) {
    const float* x    = (const float*)d_in[0];
    const float* we   = (const float*)d_in[1];
    const float* pg   = (const float*)d_in[2];
    const float* psx  = (const float*)d_in[3];
    const float* psy  = (const float*)d_in[4];
    const float* wm   = (const float*)d_in[5];
    const float* lowt = (const float*)d_in[6];
    const float* hit  = (const float*)d_in[7];
    float* mats = (float*)d_ws;      // 48 floats
    float* outp = (float*)d_out;

    // gaussian 3x3 (sigma=3), normalized (double, like numpy)
    double e1 = exp(-1.0/18.0), e2 = exp(-2.0/18.0);
    double sum = 1.0 + 4.0*e1 + 4.0*e2;
    float wc = (float)(1.0/sum), wE = (float)(e1/sum), wk = (float)(e2/sum);

    k_mats<<<1, 64, 0, stream>>>(we, pg, psx, psy, mats);
    k_fused<<<dim3(512/TS, 512/TS, Bsz), dim3(NT), 0, stream>>>(
        x, mats, wm, lowt, hit, outp, wc, wE, wk);
}

// Round 4
// 53.540 us; speedup vs baseline: 2.0663x; 1.1124x over previous
//
#include <hip/hip_runtime.h>
#include <math.h>

#define Bsz 8
#define HWp (512*512)
#define TS 32
#define SG 36          // s-grid (out + halo 2)
#define MG 34          // m-grid (out + halo 1)
#define XW 40          // x window (out + halo 4)
#define BW 38          // blur window (out + halo 3)
#define NT 512
#define K2E 1442.6950408889634f   // 1000*log2(e)

#if __has_builtin(__builtin_amdgcn_exp2f)
#define EXP2F(x) __builtin_amdgcn_exp2f(x)
#else
#define EXP2F(x) __expf(0.6931471805599453f*(x))
#endif

__device__ __forceinline__ int refl(int i, int n) {
    i = (i < 0) ? -i : i;
    return (i >= n) ? (2*n - 2 - i) : i;
}

// mats[0..23]=Psx@(Pg@We), [24..47]=Psy@(Pg@We), [48..55]=hi*K2E, [56..63]=lo*K2E, [64..71]=0.5*wm
__global__ void k_mats(const float* __restrict__ we, const float* __restrict__ pg,
                       const float* __restrict__ psx, const float* __restrict__ psy,
                       const float* __restrict__ wm, const float* __restrict__ lowt,
                       const float* __restrict__ hight, float* __restrict__ mats) {
    if (threadIdx.x == 0 && blockIdx.x == 0) {
        float M1[8][3];
        for (int o = 0; o < 8; ++o)
            for (int c = 0; c < 3; ++c) {
                float a = 0.f;
                for (int k = 0; k < 8; ++k) a += pg[o*8+k] * we[k*3+c];
                M1[o][c] = a;
            }
        for (int o = 0; o < 8; ++o)
            for (int c = 0; c < 3; ++c) {
                float a = 0.f, b = 0.f;
                for (int k = 0; k < 8; ++k) { a += psx[o*8+k]*M1[k][c]; b += psy[o*8+k]*M1[k][c]; }
                mats[o*3+c]      = a;
                mats[24 + o*3+c] = b;
            }
        for (int o = 0; o < 8; ++o) {
            mats[48+o] = hight[o] * K2E;
            mats[56+o] = lowt[o]  * K2E;
            mats[64+o] = 0.5f * wm[o];
        }
    }
}

__global__ __launch_bounds__(NT) void k_fused(
    const float* __restrict__ x, const float* __restrict__ mats,
    float* __restrict__ out, float wc, float wE, float wk)
{
    __shared__ float sm1[3*XW*XW];   // A/B: x window ; C+: sS(1296) | mS(1156)
    __shared__ float blb[3*BW*BW];

    const int b  = blockIdx.z;
    const int x0 = blockIdx.x*TS, y0 = blockIdx.y*TS;
    const int t  = threadIdx.x;
    const bool inter = (blockIdx.x > 0) && ((int)blockIdx.x < (int)gridDim.x-1) &&
                       (blockIdx.y > 0) && ((int)blockIdx.y < (int)gridDim.y-1);

    const float* xb = x + (size_t)b*3*HWp;

    // ---- phase A: x window (reflect) -> sm1 ----
    if (inter) {
        // vectorized: rows are 40 floats = 10 float4, base (x0-4) is 16B-aligned
        const float* xo = xb + (size_t)(y0-4)*512 + (x0-4);
        for (int i = t; i < 3*XW*10; i += NT) {
            int c = i/400; int j = i - c*400; int r = j/10; int q = j - r*10;
            float4 v = *(const float4*)(xo + (size_t)c*HWp + r*512 + q*4);
            *(float4*)&sm1[c*(XW*XW) + r*XW + q*4] = v;
        }
    } else {
        for (int i = t; i < XW*XW; i += NT) {
            int r = i/XW, cc = i - r*XW;
            size_t off = (size_t)refl(y0-4+r,512)*512 + refl(x0-4+cc,512);
            #pragma unroll
            for (int c = 0; c < 3; ++c)
                sm1[c*(XW*XW)+i] = xb[(size_t)c*HWp + off];
        }
    }
    __syncthreads();

    // ---- phase B: gaussian blur (double-reflect via window) -> blb ----
    if (inter) {
        for (int i = t; i < BW*BW; i += NT) {
            int r = i/BW, cc = i - r*BW;
            const int base = (r+1)*XW + (cc+1);
            #pragma unroll
            for (int c = 0; c < 3; ++c) {
                const float* xp = &sm1[c*(XW*XW) + base];
                blb[c*(BW*BW)+i] =
                    wk*(xp[-XW-1]+xp[-XW+1]+xp[XW-1]+xp[XW+1]) +
                    wE*(xp[-XW]+xp[-1]+xp[1]+xp[XW]) + wc*xp[0];
            }
        }
    } else {
        for (int i = t; i < BW*BW; i += NT) {
            int r = i/BW, cc = i - r*BW;
            int iy = refl(y0-3+r,512) - (y0-4);
            int ix = refl(x0-3+cc,512) - (x0-4);
            const int base = iy*XW + ix;
            #pragma unroll
            for (int c = 0; c < 3; ++c) {
                const float* xp = &sm1[c*(XW*XW) + base];
                blb[c*(BW*BW)+i] =
                    wk*(xp[-XW-1]+xp[-XW+1]+xp[XW-1]+xp[XW+1]) +
                    wE*(xp[-XW]+xp[-1]+xp[1]+xp[XW]) + wc*xp[0];
            }
        }
    }
    __syncthreads();

    // ---- phase C: sobel -> 8ch gx/gy/mag (regs, PINNED) + octant(2b) + s -> sS ----
    float mg[3][8];
    unsigned qk[3];
    #pragma unroll
    for (int it = 0; it < 3; ++it) {
        int i = t + it*NT;
        qk[it] = 0;
        if (i < SG*SG) {
            int r = i/SG, cc = i - r*SG;
            float txv[3], tyv[3];
            #pragma unroll
            for (int c = 0; c < 3; ++c) {
                const float* bp = &blb[c*(BW*BW) + r*BW + cc];
                float v00=bp[0],    v01=bp[1],      v02=bp[2];
                float v10=bp[BW],                   v12=bp[BW+2];
                float v20=bp[2*BW], v21=bp[2*BW+1], v22=bp[2*BW+2];
                txv[c] = 0.5f*(v02-v00) + (v12-v10) + 0.5f*(v22-v20);
                tyv[c] = 0.5f*(v20-v00) + (v21-v01) + 0.5f*(v22-v02);
            }
            float s = 0.f; unsigned pk = 0;
            #pragma unroll
            for (int o = 0; o < 8; ++o) {
                float gx  = mats[o*3]*txv[0]    + mats[o*3+1]*txv[1]    + mats[o*3+2]*txv[2];
                float gy  = mats[24+o*3]*tyv[0] + mats[24+o*3+1]*tyv[1] + mats[24+o*3+2]*tyv[2];
                float mgv = __builtin_amdgcn_sqrtf(gx*gx + gy*gy + 1e-10f);
                mg[it][o] = mgv; s += mgv;
                float ax = fabsf(gx), ay = fabsf(gy);
                unsigned qo;
                if (ay <= 0.41421356237309503f*ax)      qo = 0u;         // E/W axis
                else if (ax <= 0.41421356237309503f*ay) qo = 2u;         // N/S axis
                else qo = ((gx >= 0.f) == (gy >= 0.f)) ? 1u : 3u;        // diagonals
                pk |= qo << (2*o);
            }
            qk[it] = pk;
            // pin: forbid rematerialization of the above in phase D
            #pragma unroll
            for (int o = 0; o < 8; ++o) { asm volatile("" : "+v"(mg[it][o])); }
            asm volatile("" : "+v"(qk[it]));
            int gy_ = y0-2+r, gx_ = x0-2+cc;
            bool inimg = ((unsigned)gy_ < 512u) && ((unsigned)gx_ < 512u);
            sm1[i] = inimg ? s : 0.f;      // sS (x window dead after B)
        }
    }
    __syncthreads();

    // ---- phase D: NMS + soft double threshold + merge -> mS ----
    {
        float* sS = sm1;
        float* mS = sm1 + SG*SG;
        const float* hiK = mats + 48;
        const float* loK = mats + 56;
        const float* wmh = mats + 64;
        #pragma unroll
        for (int it = 0; it < 3; ++it) {
            int i = t + it*NT;
            if (i < SG*SG) {
                int r = i/SG, cc = i - r*SG;
                if (r >= 1 && r < SG-1 && cc >= 1 && cc < SG-1) {
                    const float* sp = &sS[i];
                    float sc = sp[0];
                    unsigned mask = 0;
                    mask |= ((sc > sp[1])    && (sc > sp[-1]))    ? 1u : 0u;  // E/W
                    mask |= ((sc > sp[SG+1]) && (sc > sp[-SG-1])) ? 2u : 0u;  // SE/NW
                    mask |= ((sc > sp[SG])   && (sc > sp[-SG]))   ? 4u : 0u;  // S/N
                    mask |= ((sc > sp[SG-1]) && (sc > sp[-SG+1])) ? 8u : 0u;  // SW/NE
                    unsigned pk = qk[it];
                    float m = 0.f;
                    #pragma unroll
                    for (int o = 0; o < 8; ++o) {
                        float nms = ((mask >> ((pk >> (2*o)) & 3u)) & 1u) ? mg[it][o] : 0.f;
                        // 0.5*(sig(1000(nms-hi)) + sig(1000(nms-lo))), exp2-folded
                        float shi = __builtin_amdgcn_rcpf(1.f + EXP2F(fmaf(nms, -K2E, hiK[o])));
                        float slo = __builtin_amdgcn_rcpf(1.f + EXP2F(fmaf(nms, -K2E, loK[o])));
                        m += wmh[o]*(shi + slo);
                    }
                    mS[(r-1)*MG + (cc-1)] = m;
                }
            }
        }
    }
    __syncthreads();

    // ---- phase E: one-step hysteresis (reflect) -> out ----
    {
        const float* mS = sm1 + SG*SG;
        for (int i2 = t; i2 < TS*TS; i2 += NT) {
            int ty_ = i2/TS, tx_ = i2 - ty_*TS;
            int y = y0 + ty_, xg = x0 + tx_;
            const float* mp = &mS[(ty_+1)*MG + (tx_+1)];
            float mc = mp[0];
            float hy = 0.f;
            if (inter) {
                #pragma unroll
                for (int dy = -1; dy <= 1; ++dy)
                    #pragma unroll
                    for (int dx = -1; dx <= 1; ++dx)
                        hy += (mp[dy*MG+dx] == 1.0f) ? 1.25f : 0.f;
            } else {
                #pragma unroll
                for (int dy = -1; dy <= 1; ++dy)
                    #pragma unroll
                    for (int dx = -1; dx <= 1; ++dx) {
                        int ly = refl(y+dy,512) - (y0-1);
                        int lx = refl(xg+dx,512) - (x0-1);
                        hy += (mS[ly*MG+lx] == 1.0f) ? 1.25f : 0.f;
                    }
            }
            float strong = (mc == 1.0f) ? mc : 0.f;
            out[(size_t)b*HWp + (size_t)y*512 + xg] =
                (((hy > 1.0f) && (mc == 0.5f)) ? mc : 0.f) + strong;
        }
    }
}

extern "C" void kernel_launch(void* const* d_in, const int* in_sizes, int n_in,
                              void* d_out, int out_size, void* d_ws, size_t ws_size,
                              hipStream_t stream) {
    const float* x    = (const float*)d_in[0];
    const float* we   = (const float*)d_in[1];
    const float* pg   = (const float*)d_in[2];
    const float* psx  = (const float*)d_in[3];
    const float* psy  = (const float*)d_in[4];
    const float* wm   = (const float*)d_in[5];
    const float* lowt = (const float*)d_in[6];
    const float* hit  = (const float*)d_in[7];
    float* mats = (float*)d_ws;      // 72 floats
    float* outp = (float*)d_out;

    // gaussian 3x3 (sigma=3), normalized (double, like numpy)
    double e1 = exp(-1.0/18.0), e2 = exp(-2.0/18.0);
    double sum = 1.0 + 4.0*e1 + 4.0*e2;
    float wc = (float)(1.0/sum), wE = (float)(e1/sum), wk = (float)(e2/sum);

    k_mats<<<1, 64, 0, stream>>>(we, pg, psx, psy, wm, lowt, hit, mats);
    k_fused<<<dim3(512/TS, 512/TS, Bsz), dim3(NT), 0, stream>>>(
        x, mats, outp, wc, wE, wk);
}

// Round 5
// 52.434 us; speedup vs baseline: 2.1099x; 1.0211x over previous
//
#include <hip/hip_runtime.h>
#include <math.h>

#define Bsz 8
#define HWp (512*512)
#define TS 32
#define SG 36          // s-grid (out + halo 2)
#define MG 34          // m-grid (out + halo 1)
#define XW 40          // x window (out + halo 4)
#define BW 38          // blur window (out + halo 3)
#define NT 512
#define K2E 1442.6950408889634f   // 1000*log2(e)
#define T2q 0.17157287525380993f  // tan^2(22.5 deg)

#if __has_builtin(__builtin_amdgcn_exp2f)
#define EXP2F(x) __builtin_amdgcn_exp2f(x)
#else
#define EXP2F(x) __expf(0.6931471805599453f*(x))
#endif

__device__ __forceinline__ int refl(int i, int n) {
    i = (i < 0) ? -i : i;
    return (i >= n) ? (2*n - 2 - i) : i;
}

// mats[0..23]=Psx@(Pg@We), [24..47]=Psy@(Pg@We), [48..55]=hi*K2E, [56..63]=lo*K2E, [64..71]=0.5*wm
__global__ void k_mats(const float* __restrict__ we, const float* __restrict__ pg,
                       const float* __restrict__ psx, const float* __restrict__ psy,
                       const float* __restrict__ wm, const float* __restrict__ lowt,
                       const float* __restrict__ hight, float* __restrict__ mats) {
    if (threadIdx.x == 0 && blockIdx.x == 0) {
        float M1[8][3];
        for (int o = 0; o < 8; ++o)
            for (int c = 0; c < 3; ++c) {
                float a = 0.f;
                for (int k = 0; k < 8; ++k) a += pg[o*8+k] * we[k*3+c];
                M1[o][c] = a;
            }
        for (int o = 0; o < 8; ++o)
            for (int c = 0; c < 3; ++c) {
                float a = 0.f, b = 0.f;
                for (int k = 0; k < 8; ++k) { a += psx[o*8+k]*M1[k][c]; b += psy[o*8+k]*M1[k][c]; }
                mats[o*3+c]      = a;
                mats[24 + o*3+c] = b;
            }
        for (int o = 0; o < 8; ++o) {
            mats[48+o] = hight[o] * K2E;
            mats[56+o] = lowt[o]  * K2E;
            mats[64+o] = 0.5f * wm[o];
        }
    }
}

__global__ __launch_bounds__(NT) void k_fused(
    const float* __restrict__ x, const float* __restrict__ mats,
    float* __restrict__ out, float wc, float wE, float wk)
{
    __shared__ float sm1[3*XW*XW];   // A/B: x window ; C+: sS(1296) | mS(1156)
    __shared__ float blb[3*BW*BW];
    __shared__ int anyS;

    const int b  = blockIdx.z;
    const int x0 = blockIdx.x*TS, y0 = blockIdx.y*TS;
    const int t  = threadIdx.x;
    const bool inter = (blockIdx.x > 0) && ((int)blockIdx.x < (int)gridDim.x-1) &&
                       (blockIdx.y > 0) && ((int)blockIdx.y < (int)gridDim.y-1);

    if (t == 0) anyS = 0;

    const float* xb = x + (size_t)b*3*HWp;

    // ---- phase A: x window (reflect) -> sm1 ----
    if (inter) {
        const float* xo = xb + (size_t)(y0-4)*512 + (x0-4);
        for (int i = t; i < 3*XW*10; i += NT) {
            int c = i/400; int j = i - c*400; int r = j/10; int q = j - r*10;
            float4 v = *(const float4*)(xo + (size_t)c*HWp + r*512 + q*4);
            *(float4*)&sm1[c*(XW*XW) + r*XW + q*4] = v;
        }
    } else {
        for (int i = t; i < XW*XW; i += NT) {
            int r = i/XW, cc = i - r*XW;
            size_t off = (size_t)refl(y0-4+r,512)*512 + refl(x0-4+cc,512);
            #pragma unroll
            for (int c = 0; c < 3; ++c)
                sm1[c*(XW*XW)+i] = xb[(size_t)c*HWp + off];
        }
    }
    __syncthreads();

    // ---- phase B: gaussian blur -> blb ----
    if (inter) {
        // column-run sliding: thread = (col, 3-row group), vertical-pair factoring
        if (t < 494) {
            int g = t/38, cb = t - g*38, r0 = 3*g;
            #pragma unroll
            for (int c = 0; c < 3; ++c) {
                const float* col = &sm1[c*(XW*XW) + cb];
                float* bo = &blb[c*(BW*BW) + cb];
                float a0 = col[r0*XW],     a1 = col[r0*XW+1],     a2 = col[r0*XW+2];
                float e0 = col[(r0+1)*XW], e1 = col[(r0+1)*XW+1], e2 = col[(r0+1)*XW+2];
                #pragma unroll
                for (int ir = 0; ir < 3; ++ir) {
                    int r = r0 + ir;
                    if (r < BW) {
                        float f0 = col[(r+2)*XW], f1 = col[(r+2)*XW+1], f2 = col[(r+2)*XW+2];
                        float t0 = a0+f0, t1 = a1+f1, t2 = a2+f2;
                        float u = t0+t2, v = e0+e2, w = t1+v;
                        bo[r*BW] = wk*u + wE*w + wc*e1;
                        a0=e0; a1=e1; a2=e2; e0=f0; e1=f1; e2=f2;
                    }
                }
            }
        }
    } else {
        for (int i = t; i < BW*BW; i += NT) {
            int r = i/BW, cc = i - r*BW;
            int iy = refl(y0-3+r,512) - (y0-4);
            int ix = refl(x0-3+cc,512) - (x0-4);
            const int base = iy*XW + ix;
            #pragma unroll
            for (int c = 0; c < 3; ++c) {
                const float* xp = &sm1[c*(XW*XW) + base];
                blb[c*(BW*BW)+i] =
                    wk*(xp[-XW-1]+xp[-XW+1]+xp[XW-1]+xp[XW+1]) +
                    wE*(xp[-XW]+xp[-1]+xp[1]+xp[XW]) + wc*xp[0];
            }
        }
    }
    __syncthreads();

    // ---- phase C: sobel via rolling row-diff/row-smooth regs -> mag/octant (regs) + s -> sS ----
    float mg[3][8];
    unsigned qk[3];
    const int gC = t/36, csC = t - gC*36, r0C = 3*gC;
    const bool actC = (t < 432);
    if (actC) {
        float txv[3][3], tyv[3][3];
        #pragma unroll
        for (int c = 0; c < 3; ++c) {
            const float* blc = &blb[c*(BW*BW) + csC];
            float p0 = blc[r0C*BW],     p1 = blc[r0C*BW+1],     p2 = blc[r0C*BW+2];
            float q0 = blc[(r0C+1)*BW], q1 = blc[(r0C+1)*BW+1], q2 = blc[(r0C+1)*BW+2];
            float D0 = p2-p0, E0 = fmaf(0.5f, p0+p2, p1);
            float D1 = q2-q0, E1 = fmaf(0.5f, q0+q2, q1);
            #pragma unroll
            for (int ir = 0; ir < 3; ++ir) {
                const float* wr = &blc[(r0C+2+ir)*BW];
                float w0 = wr[0], w1 = wr[1], w2 = wr[2];
                float D2 = w2-w0, E2 = fmaf(0.5f, w0+w2, w1);
                txv[ir][c] = fmaf(0.5f, D0+D2, D1);
                tyv[ir][c] = E2 - E0;
                D0 = D1; D1 = D2; E0 = E1; E1 = E2;
            }
        }
        #pragma unroll
        for (int ir = 0; ir < 3; ++ir) {
            float s = 0.f; unsigned pk = 0;
            #pragma unroll
            for (int o = 0; o < 8; ++o) {
                float gx = mats[o*3]*txv[ir][0]    + mats[o*3+1]*txv[ir][1]    + mats[o*3+2]*txv[ir][2];
                float gy = mats[24+o*3]*tyv[ir][0] + mats[24+o*3+1]*tyv[ir][1] + mats[24+o*3+2]*tyv[ir][2];
                float gx2 = gx*gx, gy2 = gy*gy;
                float mag = __builtin_amdgcn_sqrtf(gx2 + gy2 + 1e-10f);
                mg[ir][o] = mag; s += mag;
                // octant (2-bit axis-pair): squares + sign-bit xor; boundaries generic
                unsigned dv = 1u | (((__float_as_uint(gx) ^ __float_as_uint(gy)) >> 30) & 2u);
                unsigned qo = (gx2 <= T2q*gy2) ? 2u : dv;
                qo = (gy2 <= T2q*gx2) ? 0u : qo;
                pk |= qo << (2*o);
            }
            qk[ir] = pk;
            #pragma unroll
            for (int o = 0; o < 8; ++o) { asm volatile("" : "+v"(mg[ir][o])); }
            asm volatile("" : "+v"(qk[ir]));
            int rr = r0C + ir;
            int gy_ = y0-2+rr, gx_ = x0-2+csC;
            bool inimg = ((unsigned)gy_ < 512u) && ((unsigned)gx_ < 512u);
            sm1[rr*SG + csC] = inimg ? s : 0.f;   // sS (x window dead after B)
        }
    }
    __syncthreads();

    // ---- phase D: NMS + soft double threshold + merge -> mS ----
    {
        const float* sS = sm1;
        float* mS = sm1 + SG*SG;
        const float* hiK = mats + 48;
        const float* loK = mats + 56;
        const float* wmh = mats + 64;
        if (actC && csC >= 1 && csC <= 34) {
            #pragma unroll
            for (int ir = 0; ir < 3; ++ir) {
                int r = r0C + ir;
                if (r >= 1 && r <= 34) {
                    const float* sp = &sS[r*SG + csC];
                    float sc = sp[0];
                    unsigned mask = 0;
                    mask |= ((sc > sp[1])    && (sc > sp[-1]))    ? 1u : 0u;  // E/W
                    mask |= ((sc > sp[SG+1]) && (sc > sp[-SG-1])) ? 2u : 0u;  // SE/NW
                    mask |= ((sc > sp[SG])   && (sc > sp[-SG]))   ? 4u : 0u;  // S/N
                    mask |= ((sc > sp[SG-1]) && (sc > sp[-SG+1])) ? 8u : 0u;  // SW/NE
                    unsigned pk = qk[ir];
                    float m = 0.f;
                    #pragma unroll
                    for (int o = 0; o < 8; ++o) {
                        float nms = ((mask >> ((pk >> (2*o)) & 3u)) & 1u) ? mg[ir][o] : 0.f;
                        float shi = __builtin_amdgcn_rcpf(1.f + EXP2F(fmaf(nms, -K2E, hiK[o])));
                        float slo = __builtin_amdgcn_rcpf(1.f + EXP2F(fmaf(nms, -K2E, loK[o])));
                        m += wmh[o]*(shi + slo);
                    }
                    mS[(r-1)*MG + (csC-1)] = m;
                    if (m == 1.0f) anyS = 1;
                }
            }
        }
    }
    __syncthreads();

    // ---- phase E: one-step hysteresis (reflect) -> out; skip if no strong pixel ----
    {
        const float* mS = sm1 + SG*SG;
        float* op = out + (size_t)b*HWp;
        if (anyS == 0) {
            // no m==1.0 in the 34^2 window covering all 3x3 neighborhoods -> hyst==0 -> out==0
            #pragma unroll
            for (int i2 = t; i2 < TS*TS; i2 += NT) {
                int ty_ = i2>>5, tx_ = i2&31;
                op[(size_t)(y0+ty_)*512 + (x0+tx_)] = 0.f;
            }
        } else {
            for (int i2 = t; i2 < TS*TS; i2 += NT) {
                int ty_ = i2>>5, tx_ = i2&31;
                int y = y0 + ty_, xg = x0 + tx_;
                const float* mp = &mS[(ty_+1)*MG + (tx_+1)];
                float mc = mp[0];
                float hy = 0.f;
                if (inter) {
                    #pragma unroll
                    for (int dy = -1; dy <= 1; ++dy)
                        #pragma unroll
                        for (int dx = -1; dx <= 1; ++dx)
                            hy += (mp[dy*MG+dx] == 1.0f) ? 1.25f : 0.f;
                } else {
                    #pragma unroll
                    for (int dy = -1; dy <= 1; ++dy)
                        #pragma unroll
                        for (int dx = -1; dx <= 1; ++dx) {
                            int ly = refl(y+dy,512) - (y0-1);
                            int lx = refl(xg+dx,512) - (x0-1);
                            hy += (mS[ly*MG+lx] == 1.0f) ? 1.25f : 0.f;
                        }
                }
                float strong = (mc == 1.0f) ? mc : 0.f;
                op[(size_t)y*512 + xg] =
                    (((hy > 1.0f) && (mc == 0.5f)) ? mc : 0.f) + strong;
            }
        }
    }
}

extern "C" void kernel_launch(void* const* d_in, const int* in_sizes, int n_in,
                              void* d_out, int out_size, void* d_ws, size_t ws_size,
                              hipStream_t stream) {
    const float* x    = (const float*)d_in[0];
    const float* we   = (const float*)d_in[1];
    const float* pg   = (const float*)d_in[2];
    const float* psx  = (const float*)d_in[3];
    const float* psy  = (const float*)d_in[4];
    const float* wm   = (const float*)d_in[5];
    const float* lowt = (const float*)d_in[6];
    const float* hit  = (const float*)d_in[7];
    float* mats = (float*)d_ws;      // 72 floats
    float* outp = (float*)d_out;

    // gaussian 3x3 (sigma=3), normalized (double, like numpy)
    double e1 = exp(-1.0/18.0), e2 = exp(-2.0/18.0);
    double sum = 1.0 + 4.0*e1 + 4.0*e2;
    float wc = (float)(1.0/sum), wE = (float)(e1/sum), wk = (float)(e2/sum);

    k_mats<<<1, 64, 0, stream>>>(we, pg, psx, psy, wm, lowt, hit, mats);
    k_fused<<<dim3(512/TS, 512/TS, Bsz), dim3(NT), 0, stream>>>(
        x, mats, outp, wc, wE, wk);
}

// Round 6
// 52.168 us; speedup vs baseline: 2.1207x; 1.0051x over previous
//
#include <hip/hip_runtime.h>
#include <math.h>

#define Bsz 8
#define HWp (512*512)
#define TS 32
#define SG 36          // s-grid (out + halo 2)
#define MG 34          // m-grid (out + halo 1)
#define XW 40          // x window (out + halo 4)
#define BW 38          // blur window (out + halo 3)
#define NT 512
#define K2E 1442.6950408889634f   // 1000*log2(e)
#define T2q 0.17157287525380993f  // tan^2(22.5 deg)

typedef float f2 __attribute__((ext_vector_type(2)));

#if __has_builtin(__builtin_amdgcn_exp2f)
#define EXP2F(x) __builtin_amdgcn_exp2f(x)
#else
#define EXP2F(x) __expf(0.6931471805599453f*(x))
#endif

__device__ __forceinline__ int refl(int i, int n) {
    i = (i < 0) ? -i : i;
    return (i >= n) ? (2*n - 2 - i) : i;
}

// mats layout (floats):
//  [0..23]   A   = Psx@(Pg@We) row-major [o][c]
//  [24..47]  B   = Psy@(Pg@We)
//  [48..55]  hi*K2E   [56..63] lo*K2E   [64..71] 0.5*wm
//  [72..119] Apk: pairs (A[2j][k],A[2j+1][k]) at [(j*3+k)*2]
//  [120..167] Bpk: same for B
__global__ void k_mats(const float* __restrict__ we, const float* __restrict__ pg,
                       const float* __restrict__ psx, const float* __restrict__ psy,
                       const float* __restrict__ wm, const float* __restrict__ lowt,
                       const float* __restrict__ hight, float* __restrict__ mats) {
    if (threadIdx.x == 0 && blockIdx.x == 0) {
        float M1[8][3];
        for (int o = 0; o < 8; ++o)
            for (int c = 0; c < 3; ++c) {
                float a = 0.f;
                for (int k = 0; k < 8; ++k) a += pg[o*8+k] * we[k*3+c];
                M1[o][c] = a;
            }
        for (int o = 0; o < 8; ++o)
            for (int c = 0; c < 3; ++c) {
                float a = 0.f, b = 0.f;
                for (int k = 0; k < 8; ++k) { a += psx[o*8+k]*M1[k][c]; b += psy[o*8+k]*M1[k][c]; }
                mats[o*3+c]      = a;
                mats[24 + o*3+c] = b;
            }
        for (int o = 0; o < 8; ++o) {
            mats[48+o] = hight[o] * K2E;
            mats[56+o] = lowt[o]  * K2E;
            mats[64+o] = 0.5f * wm[o];
        }
        for (int j = 0; j < 4; ++j)
            for (int k = 0; k < 3; ++k)
                for (int e = 0; e < 2; ++e) {
                    mats[72  + (j*3+k)*2 + e] = mats[(2*j+e)*3 + k];
                    mats[120 + (j*3+k)*2 + e] = mats[24 + (2*j+e)*3 + k];
                }
    }
}

__global__ __launch_bounds__(NT) void k_fused(
    const float* __restrict__ x, const float* __restrict__ mats,
    float* __restrict__ out, float wc, float wE, float wk)
{
    __shared__ float sm1[3*XW*XW];   // A/B: x window ; C+: sS(1296) | mS(1156)
    __shared__ float blb[3*BW*BW];
    __shared__ int anyS;

    const int b  = blockIdx.z;
    const int x0 = blockIdx.x*TS, y0 = blockIdx.y*TS;
    const int t  = threadIdx.x;
    const bool inter = (blockIdx.x > 0) && ((int)blockIdx.x < (int)gridDim.x-1) &&
                       (blockIdx.y > 0) && ((int)blockIdx.y < (int)gridDim.y-1);

    if (t == 0) anyS = 0;

    const float* xb = x + (size_t)b*3*HWp;

    // ---- phase A: x window (reflect) -> sm1 ----
    if (inter) {
        const float* xo = xb + (size_t)(y0-4)*512 + (x0-4);
        for (int i = t; i < 3*XW*10; i += NT) {
            int c = i/400; int j = i - c*400; int r = j/10; int q = j - r*10;
            float4 v = *(const float4*)(xo + (size_t)c*HWp + r*512 + q*4);
            *(float4*)&sm1[c*(XW*XW) + r*XW + q*4] = v;
        }
    } else {
        for (int i = t; i < XW*XW; i += NT) {
            int r = i/XW, cc = i - r*XW;
            size_t off = (size_t)refl(y0-4+r,512)*512 + refl(x0-4+cc,512);
            #pragma unroll
            for (int c = 0; c < 3; ++c)
                sm1[c*(XW*XW)+i] = xb[(size_t)c*HWp + off];
        }
    }
    __syncthreads();

    // ---- phase B: gaussian blur -> blb ----
    if (inter) {
        if (t < 494) {
            int g = t/38, cb = t - g*38, r0 = 3*g;
            #pragma unroll
            for (int c = 0; c < 3; ++c) {
                const float* col = &sm1[c*(XW*XW) + cb];
                float* bo = &blb[c*(BW*BW) + cb];
                float a0 = col[r0*XW],     a1 = col[r0*XW+1],     a2 = col[r0*XW+2];
                float e0 = col[(r0+1)*XW], e1 = col[(r0+1)*XW+1], e2 = col[(r0+1)*XW+2];
                #pragma unroll
                for (int ir = 0; ir < 3; ++ir) {
                    int r = r0 + ir;
                    if (r < BW) {
                        float f0 = col[(r+2)*XW], f1 = col[(r+2)*XW+1], f2v = col[(r+2)*XW+2];
                        float t0 = a0+f0, t1 = a1+f1, t2 = a2+f2v;
                        float u = t0+t2, v = e0+e2, w = t1+v;
                        bo[r*BW] = wk*u + wE*w + wc*e1;
                        a0=e0; a1=e1; a2=e2; e0=f0; e1=f1; e2=f2v;
                    }
                }
            }
        }
    } else {
        for (int i = t; i < BW*BW; i += NT) {
            int r = i/BW, cc = i - r*BW;
            int iy = refl(y0-3+r,512) - (y0-4);
            int ix = refl(x0-3+cc,512) - (x0-4);
            const int base = iy*XW + ix;
            #pragma unroll
            for (int c = 0; c < 3; ++c) {
                const float* xp = &sm1[c*(XW*XW) + base];
                blb[c*(BW*BW)+i] =
                    wk*(xp[-XW-1]+xp[-XW+1]+xp[XW-1]+xp[XW+1]) +
                    wE*(xp[-XW]+xp[-1]+xp[1]+xp[XW]) + wc*xp[0];
            }
        }
    }
    __syncthreads();

    // ---- phase C: sobel via rolling regs -> mag/octant (regs, pinned) + s -> sS ----
    float mg[3][8];
    unsigned qk[3];
    const int gC = t/36, csC = t - gC*36, r0C = 3*gC;
    const bool actC = (t < 432);
    if (actC) {
        float txv[3][3], tyv[3][3];
        #pragma unroll
        for (int c = 0; c < 3; ++c) {
            const float* blc = &blb[c*(BW*BW) + csC];
            float p0 = blc[r0C*BW],     p1 = blc[r0C*BW+1],     p2 = blc[r0C*BW+2];
            float q0 = blc[(r0C+1)*BW], q1 = blc[(r0C+1)*BW+1], q2 = blc[(r0C+1)*BW+2];
            float D0 = p2-p0, E0 = fmaf(0.5f, p0+p2, p1);
            float D1 = q2-q0, E1 = fmaf(0.5f, q0+q2, q1);
            #pragma unroll
            for (int ir = 0; ir < 3; ++ir) {
                const float* wr = &blc[(r0C+2+ir)*BW];
                float w0 = wr[0], w1 = wr[1], w2 = wr[2];
                float D2 = w2-w0, E2 = fmaf(0.5f, w0+w2, w1);
                txv[ir][c] = fmaf(0.5f, D0+D2, D1);
                tyv[ir][c] = E2 - E0;
                D0 = D1; D1 = D2; E0 = E1; E1 = E2;
            }
        }
        const f2* A2 = (const f2*)(mats + 72);
        const f2* B2 = (const f2*)(mats + 120);
        #pragma unroll
        for (int ir = 0; ir < 3; ++ir) {
            f2 s2 = {0.f, 0.f};
            unsigned pk = 0;
            #pragma unroll
            for (int j = 0; j < 4; ++j) {
                f2 gx = A2[j*3+0]*txv[ir][0] + A2[j*3+1]*txv[ir][1] + A2[j*3+2]*txv[ir][2];
                f2 gy = B2[j*3+0]*tyv[ir][0] + B2[j*3+1]*tyv[ir][1] + B2[j*3+2]*tyv[ir][2];
                f2 gx2 = gx*gx, gy2 = gy*gy;
                f2 r2 = gx2 + gy2 + (f2){1e-10f, 1e-10f};
                float m0 = __builtin_amdgcn_sqrtf(r2.x);
                float m1 = __builtin_amdgcn_sqrtf(r2.y);
                mg[ir][2*j] = m0; mg[ir][2*j+1] = m1;
                s2 += (f2){m0, m1};
                unsigned d0 = 1u | (((__float_as_uint(gx.x) ^ __float_as_uint(gy.x)) >> 30) & 2u);
                unsigned q0 = (gx2.x <= T2q*gy2.x) ? 2u : d0;
                q0 = (gy2.x <= T2q*gx2.x) ? 0u : q0;
                unsigned d1 = 1u | (((__float_as_uint(gx.y) ^ __float_as_uint(gy.y)) >> 30) & 2u);
                unsigned q1 = (gx2.y <= T2q*gy2.y) ? 2u : d1;
                q1 = (gy2.y <= T2q*gx2.y) ? 0u : q1;
                pk |= (q0 << (4*j)) | (q1 << (4*j+2));
            }
            qk[ir] = pk;
            #pragma unroll
            for (int o = 0; o < 8; ++o) { asm volatile("" : "+v"(mg[ir][o])); }
            asm volatile("" : "+v"(qk[ir]));
            int rr = r0C + ir;
            int gy_ = y0-2+rr, gx_ = x0-2+csC;
            bool inimg = ((unsigned)gy_ < 512u) && ((unsigned)gx_ < 512u);
            sm1[rr*SG + csC] = inimg ? (s2.x + s2.y) : 0.f;
        }
    }
    __syncthreads();

    // ---- phase D: NMS + soft double threshold + merge -> mS ----
    bool anyL = false;
    {
        const float* sS = sm1;
        float* mS = sm1 + SG*SG;
        const f2* hiK2 = (const f2*)(mats + 48);
        const f2* loK2 = (const f2*)(mats + 56);
        const f2* wm2  = (const f2*)(mats + 64);
        if (actC && csC >= 1 && csC <= 34) {
            // rolled 3-row x 3-col register window over s
            int ra = r0C-1 < 0 ? 0 : r0C-1;
            int rb = r0C;
            int rc = r0C+1;
            const float* pa = &sS[ra*SG + csC];
            const float* pb = &sS[rb*SG + csC];
            const float* pc = &sS[rc*SG + csC];
            float l0=pa[-1], c0=pa[0], r0v=pa[1];
            float l1=pb[-1], c1=pb[0], r1v=pb[1];
            float l2=pc[-1], c2=pc[0], r2v=pc[1];
            #pragma unroll
            for (int ir = 0; ir < 3; ++ir) {
                int r = r0C + ir;
                if (r >= 1 && r <= 34) {
                    float sc = c1;
                    unsigned mask = 0;
                    mask |= ((sc > r1v) && (sc > l1)) ? 1u : 0u;  // E/W
                    mask |= ((sc > r2v) && (sc > l0)) ? 2u : 0u;  // SE/NW
                    mask |= ((sc > c2)  && (sc > c0)) ? 4u : 0u;  // S/N
                    mask |= ((sc > l2)  && (sc > r0v)) ? 8u : 0u; // SW/NE
                    unsigned pk = qk[ir];
                    f2 acc = {0.f, 0.f};
                    #pragma unroll
                    for (int j = 0; j < 4; ++j) {
                        unsigned ii = pk >> (4*j);
                        f2 nms;
                        nms.x = ((mask >> (ii & 3u)) & 1u)      ? mg[ir][2*j]   : 0.f;
                        nms.y = ((mask >> ((ii>>2) & 3u)) & 1u) ? mg[ir][2*j+1] : 0.f;
                        f2 aH = nms * (f2){-K2E,-K2E} + hiK2[j];
                        f2 aL = nms * (f2){-K2E,-K2E} + loK2[j];
                        f2 sh = { __builtin_amdgcn_rcpf(1.f + EXP2F(aH.x)),
                                  __builtin_amdgcn_rcpf(1.f + EXP2F(aH.y)) };
                        f2 sl = { __builtin_amdgcn_rcpf(1.f + EXP2F(aL.x)),
                                  __builtin_amdgcn_rcpf(1.f + EXP2F(aL.y)) };
                        acc += wm2[j]*(sh + sl);
                    }
                    float m = acc.x + acc.y;
                    mS[(r-1)*MG + (csC-1)] = m;
                    anyL |= (m == 1.0f);
                }
                // roll window down one row
                if (ir < 2) {
                    int rn = r0C + 2 + ir; rn = rn > 35 ? 35 : rn;
                    const float* pn = &sS[rn*SG + csC];
                    l0=l1; c0=c1; r0v=r1v;
                    l1=l2; c1=c2; r1v=r2v;
                    l2=pn[-1]; c2=pn[0]; r2v=pn[1];
                }
            }
        }
    }
    if (anyL) anyS = 1;
    __syncthreads();

    // ---- phase E: one-step hysteresis (reflect) -> out; vector-zero fast path ----
    {
        const float* mS = sm1 + SG*SG;
        float* op = out + (size_t)b*HWp;
        if (anyS == 0) {
            if (t < 256) {
                int row = t >> 3, q = t & 7;
                float4 z = {0.f, 0.f, 0.f, 0.f};
                *(float4*)(op + (size_t)(y0+row)*512 + x0 + q*4) = z;
            }
        } else {
            for (int i2 = t; i2 < TS*TS; i2 += NT) {
                int ty_ = i2>>5, tx_ = i2&31;
                int y = y0 + ty_, xg = x0 + tx_;
                const float* mp = &mS[(ty_+1)*MG + (tx_+1)];
                float mc = mp[0];
                float hy = 0.f;
                if (inter) {
                    #pragma unroll
                    for (int dy = -1; dy <= 1; ++dy)
                        #pragma unroll
                        for (int dx = -1; dx <= 1; ++dx)
                            hy += (mp[dy*MG+dx] == 1.0f) ? 1.25f : 0.f;
                } else {
                    #pragma unroll
                    for (int dy = -1; dy <= 1; ++dy)
                        #pragma unroll
                        for (int dx = -1; dx <= 1; ++dx) {
                            int ly = refl(y+dy,512) - (y0-1);
                            int lx = refl(xg+dx,512) - (x0-1);
                            hy += (mS[ly*MG+lx] == 1.0f) ? 1.25f : 0.f;
                        }
                }
                float strong = (mc == 1.0f) ? mc : 0.f;
                op[(size_t)y*512 + xg] =
                    (((hy > 1.0f) && (mc == 0.5f)) ? mc : 0.f) + strong;
            }
        }
    }
}

extern "C" void kernel_launch(void* const* d_in, const int* in_sizes, int n_in,
                              void* d_out, int out_size, void* d_ws, size_t ws_size,
                              hipStream_t stream) {
    const float* x    = (const float*)d_in[0];
    const float* we   = (const float*)d_in[1];
    const float* pg   = (const float*)d_in[2];
    const float* psx  = (const float*)d_in[3];
    const float* psy  = (const float*)d_in[4];
    const float* wm   = (const float*)d_in[5];
    const float* lowt = (const float*)d_in[6];
    const float* hit  = (const float*)d_in[7];
    float* mats = (float*)d_ws;      // 168 floats
    float* outp = (float*)d_out;

    // gaussian 3x3 (sigma=3), normalized (double, like numpy)
    double e1 = exp(-1.0/18.0), e2 = exp(-2.0/18.0);
    double sum = 1.0 + 4.0*e1 + 4.0*e2;
    float wc = (float)(1.0/sum), wE = (float)(e1/sum), wk = (float)(e2/sum);

    k_mats<<<1, 64, 0, stream>>>(we, pg, psx, psy, wm, lowt, hit, mats);
    k_fused<<<dim3(512/TS, 512/TS, Bsz), dim3(NT), 0, stream>>>(
        x, mats, outp, wc, wE, wk);
}